// Round 2
// baseline (302.530 us; speedup 1.0000x reference)
//
#include <hip/hip_runtime.h>
#include <hip/hip_bf16.h>
#include <math.h>

typedef __bf16 bf16x8 __attribute__((ext_vector_type(8)));
typedef float f32x4 __attribute__((ext_vector_type(4)));
typedef __hip_bfloat16 bf16_t;

#define MFMA_BF16(a, b, c) __builtin_amdgcn_mfma_f32_16x16x32_bf16((a), (b), (c), 0, 0, 0)

// async global->LDS, 16B per lane; LDS dest = wave-uniform base + lane*16
__device__ __forceinline__ void async_copy16(const bf16_t* g, bf16_t* lds_base) {
  __builtin_amdgcn_global_load_lds(
      (const __attribute__((address_space(1))) unsigned int*)g,
      (__attribute__((address_space(3))) unsigned int*)lds_base,
      16, 0, 0);
}

__device__ __forceinline__ unsigned fbits(float x) { return __builtin_bit_cast(unsigned, x); }

// ---------------- fused prep: cast hidden, transpose 4 weights, concat bias ----------------
__global__ __launch_bounds__(256) void prep(
    const float* __restrict__ hidden, const float* __restrict__ Wq, const float* __restrict__ Wk,
    const float* __restrict__ Wv, const float* __restrict__ Wo,
    const float* __restrict__ bq, const float* __restrict__ bk, const float* __restrict__ bv,
    bf16_t* __restrict__ hiddenB, bf16_t* __restrict__ WqkvT, bf16_t* __restrict__ WoT,
    float* __restrict__ bqkv, float c1) {
  __shared__ float tile[64][65];
  int bid = blockIdx.x;
  const int t = threadIdx.x;
  if (bid < 8192) {  // cast hidden f32 -> bf16, float4 per thread
    const int i = bid * 256 + t;
    float4 v = ((const float4*)hidden)[i];
    union { bf16_t h[4]; ushort4 u; } cv;
    cv.h[0] = __float2bfloat16(v.x);
    cv.h[1] = __float2bfloat16(v.y);
    cv.h[2] = __float2bfloat16(v.z);
    cv.h[3] = __float2bfloat16(v.w);
    ((ushort4*)hiddenB)[i] = cv.u;
    return;
  }
  bid -= 8192;
  if (bid >= 2560) {  // bias concat: 12 blocks x 256 = 3072
    const int i = (bid - 2560) * 256 + t;
    float v;
    if (i < 2048) v = bq[i] * c1;
    else if (i < 2560) v = bk[i - 2048];
    else v = bv[i - 2560];
    bqkv[i] = v;
    return;
  }
  // weight transpose: in [2048][C] -> out [C][2048], 64x64 tiles
  const float* src;
  bf16_t* dst;
  int Cc, bx, by;
  float scale = 1.0f;
  if (bid < 1024) { src = Wq; dst = WqkvT; Cc = 2048; bx = bid & 31; by = bid >> 5; scale = c1; }
  else if (bid < 1280) { bid -= 1024; src = Wk; dst = WqkvT + (size_t)2048 * 2048; Cc = 512; bx = bid & 7; by = bid >> 3; }
  else if (bid < 1536) { bid -= 1280; src = Wv; dst = WqkvT + (size_t)2560 * 2048; Cc = 512; bx = bid & 7; by = bid >> 3; }
  else { bid -= 1536; src = Wo; dst = WoT; Cc = 2048; bx = bid & 31; by = bid >> 5; }
  const int tx = t & 63, ty = t >> 6;
  const int c0 = bx * 64, r0 = by * 64;
#pragma unroll
  for (int i = ty; i < 64; i += 4)
    tile[i][tx] = src[(size_t)(r0 + i) * Cc + c0 + tx];
  __syncthreads();
#pragma unroll
  for (int i = ty; i < 64; i += 4)
    dst[(size_t)(c0 + i) * 2048 + r0 + tx] = __float2bfloat16(tile[tx][i] * scale);
}

// ---------------- GEMM: C[M,N] = A[M,K] @ Bt[N,K]^T + bias ----------------
// v7: BK=64 (halves barrier/vmcnt-drain count vs BK=32; LDS 32KB keeps 3 blocks/CU —
// avoids m132's BK=128 occupancy trap). 128B LDS rows -> XOR chunk swizzle
// (phys_chunk = chunk ^ (row&7)) applied at the staging SOURCE address.
// K-halves processed sequentially reusing af/bf regs to hold VGPR ~constant.
// If vTp != nullptr, blocks with n0 >= 2560 write vT[b][col-2560][s] instead of C.
template <typename TOUT>
__global__ __launch_bounds__(256, 3) void gemm_bt(
    const bf16_t* __restrict__ A, const bf16_t* __restrict__ Bt,
    const float* __restrict__ bias, TOUT* __restrict__ C, bf16_t* __restrict__ vTp,
    int M, int N, int K) {
  __shared__ alignas(16) bf16_t As[128 * 64];
  __shared__ alignas(16) bf16_t Bs[128 * 64];

  const int tid = threadIdx.x;
  const int w = tid >> 6, lane = tid & 63;
  const int quad = lane >> 4, l16 = lane & 15;
  const int wm = w >> 1, wn = w & 1;
  const int m0 = blockIdx.y * 128, n0 = blockIdx.x * 128;

  f32x4 acc[4][4] = {};

  const int rr = lane >> 3;                 // row within 8-row staging chunk
  const int scol = ((lane & 7) ^ rr) * 8;   // swizzled SOURCE col (bf16 units)
  const int sx = l16 & 7;                   // row&7 for fragment reads

  for (int k0 = 0; k0 < K; k0 += 64) {
    __syncthreads();
#pragma unroll
    for (int c = 0; c < 4; ++c) {
      const int r = w * 32 + c * 8 + rr;
      async_copy16(A + (size_t)(m0 + r) * K + k0 + scol, &As[(w * 32 + c * 8) * 64]);
      async_copy16(Bt + (size_t)(n0 + r) * K + k0 + scol, &Bs[(w * 32 + c * 8) * 64]);
    }
    __syncthreads();

#pragma unroll
    for (int kh = 0; kh < 2; ++kh) {
      bf16x8 af[4], bf[4];
#pragma unroll
      for (int i = 0; i < 4; ++i) {
        af[i] = *(const bf16x8*)&As[(wm * 64 + i * 16 + l16) * 64 + (((kh * 4 + quad) ^ sx) * 8)];
        bf[i] = *(const bf16x8*)&Bs[(wn * 64 + i * 16 + l16) * 64 + (((kh * 4 + quad) ^ sx) * 8)];
      }
#pragma unroll
      for (int i = 0; i < 4; ++i)
#pragma unroll
        for (int j = 0; j < 4; ++j)
          acc[i][j] = MFMA_BF16(af[i], bf[j], acc[i][j]);
    }
  }

  if (vTp != nullptr && n0 >= 2560) {
    // v-columns -> vT[b][kv][s]; rows here are b*2048+s with 4 consecutive s per lane
#pragma unroll
    for (int i = 0; i < 4; ++i) {
      const int row = m0 + wm * 64 + i * 16 + quad * 4;
      const int bb = row >> 11, s = row & 2047;
#pragma unroll
      for (int j = 0; j < 4; ++j) {
        const int col = n0 + wn * 64 + j * 16 + l16;
        const float bv = bias[col];
        union { bf16_t h[4]; ushort4 u; } cv;
#pragma unroll
        for (int r = 0; r < 4; ++r) cv.h[r] = __float2bfloat16(acc[i][j][r] + bv);
        *(ushort4*)&vTp[((size_t)bb * 512 + (col - 2560)) * 2048 + s] = cv.u;
      }
    }
    return;
  }

#pragma unroll
  for (int i = 0; i < 4; ++i) {
    const int row = m0 + wm * 64 + i * 16 + quad * 4;
#pragma unroll
    for (int j = 0; j < 4; ++j) {
      const int col = n0 + wn * 64 + j * 16 + l16;
      const float bv = bias[col];
#pragma unroll
      for (int r = 0; r < 4; ++r) {
        const float val = acc[i][j][r] + bv;
        if constexpr (__is_same(TOUT, float)) {
          C[(size_t)(row + r) * N + col] = val;
        } else {
          C[(size_t)(row + r) * N + col] = __float2bfloat16(val);
        }
      }
    }
  }
}

// ---------------- GQA flash attention (v8: T14 reg-staged prefetch + T5 setprio) ----------------
// QKV: [B*S][3072] bf16 (q at col h*64, Wq pre-scaled by 0.125*log2e; k at 2048+g*64)
// VT: [B*512][2048] bf16 (row b*512+g*64+d, col s); O: [B*S][2048] bf16
// grid (S/64, NH/2, B) = 1024 blocks = 4/CU; 256 threads. Block covers 64 q-rows x 2 heads
// (same KV group: h = hp*2+(w&1), g = hp>>1) -> K/V staging serves 2 heads (half traffic).
// v8 change vs v7 (T14, m214v27 analog): drop global_load_lds; stage via registers --
// global_load_dwordx4 for tile t+1 issued right after the ds_writes of tile t, so the
// ~400cy L2 latency hides under the full compute phase instead of being drained between
// the two barriers. ds_write applies the XOR chunk swizzle (phys_chunk = chunk ^ (row&7))
// directly, so global reads use natural (unswizzled) columns. +T5 setprio(1) around the
// compute phase (m191: +4-7% for independent barrier-phased blocks).
// NOTE (R4/R5): latency-bound — keep 32KB LDS, 4 blocks/CU, 2 barriers/iter.
// (Round-1 resubmission: round-0 bench died on container acquisition, not the kernel.)
__global__ __launch_bounds__(256, 4) void gqa_attn(
    const bf16_t* __restrict__ QKV, const bf16_t* __restrict__ VT, bf16_t* __restrict__ O) {
  constexpr int S = 2048, HID = 2048, QKVS = 3072, HD = 64;
  const int tid = threadIdx.x;
  const int w = tid >> 6, lane = tid & 63;
  const int quad = lane >> 4, l16 = lane & 15;
  const int hp = blockIdx.y, b = blockIdx.z;
  const int h = hp * 2 + (w & 1);       // wave's head
  const int g = hp >> 1;                // shared KV group (rep=4: heads 4g..4g+3)
  const int q0 = blockIdx.x * 64 + (w >> 1) * 32;  // wave's 32 q rows

  __shared__ alignas(16) bf16_t Ks[64 * 64];
  __shared__ alignas(16) bf16_t VTs[64 * 64];
  __shared__ alignas(16) bf16_t Ps[128 * 64];

  // Q fragments in registers (B-operand layout: n=l16 -> q, k=quad*8+j); pre-scaled
  bf16x8 qf[2][2];
#pragma unroll
  for (int mt = 0; mt < 2; ++mt)
#pragma unroll
    for (int ks = 0; ks < 2; ++ks)
      qf[mt][ks] = *(const bf16x8*)&QKV[(size_t)(b * S + q0 + mt * 16 + l16) * QKVS +
                                        h * HD + ks * 32 + quad * 8];

  const int rr = lane >> 3, c7 = lane & 7;
  const int sx = l16 & 7;

  const bf16_t* Kbase = QKV + (size_t)b * S * QKVS + 2048 + g * HD;
  const bf16_t* Vbase = VT + (size_t)(b * 512 + g * HD) * S;

  // reg-staging geometry: this thread owns rows srow and srow+8 of the 64-row tile,
  // 16B chunk c7; LDS dest chunk XOR-swizzled with row&7 (= rr).
  const int srow = w * 16 + rr;
  const bf16_t* kp0 = Kbase + (size_t)srow * QKVS + c7 * 8;
  const bf16_t* kp1 = kp0 + (size_t)8 * QKVS;
  const bf16_t* vp0 = Vbase + (size_t)srow * S + c7 * 8;
  const bf16_t* vp1 = vp0 + (size_t)8 * S;
  bf16_t* KsW0 = &Ks[(srow)*64 + (c7 ^ rr) * 8];
  bf16_t* KsW1 = KsW0 + 8 * 64;
  bf16_t* VsW0 = &VTs[(srow)*64 + (c7 ^ rr) * 8];
  bf16_t* VsW1 = VsW0 + 8 * 64;

  f32x4 oacc[2][4] = {};
  f32x4 lacc[2] = {};
  bf16x8 ones;
#pragma unroll
  for (int j = 0; j < 8; ++j) ones[j] = (__bf16)1.0f;

  // prologue: issue tile-0 loads
  uint4 kr0 = *(const uint4*)kp0;
  uint4 kr1 = *(const uint4*)kp1;
  uint4 vr0 = *(const uint4*)vp0;
  uint4 vr1 = *(const uint4*)vp1;

  for (int s0 = 0; s0 < S; s0 += 64) {
    __syncthreads();  // all waves done reading the previous tile's LDS
    *(uint4*)KsW0 = kr0;
    *(uint4*)KsW1 = kr1;
    *(uint4*)VsW0 = vr0;
    *(uint4*)VsW1 = vr1;
    // issue next-tile loads now; they stay in flight across the whole compute phase.
    // wraps to tile 0 on the last iteration (harmless in-bounds reload, branchless).
    const int sn = (s0 + 64) & (S - 1);
    kr0 = *(const uint4*)(kp0 + (size_t)sn * QKVS);
    kr1 = *(const uint4*)(kp1 + (size_t)sn * QKVS);
    vr0 = *(const uint4*)(vp0 + sn);
    vr1 = *(const uint4*)(vp1 + sn);
    __syncthreads();  // ds_writes visible to all waves

    __builtin_amdgcn_s_setprio(1);
    // ---- S^T = K·Q^T (row=kv=quad*4+r, col=q=l16); p=exp2(s); pack(trunc) -> Ps[q][kv] ----
#pragma unroll
    for (int nt = 0; nt < 4; ++nt) {
      bf16x8 kf0 = *(const bf16x8*)&Ks[(nt * 16 + l16) * 64 + ((quad ^ sx) * 8)];
      bf16x8 kf1 = *(const bf16x8*)&Ks[(nt * 16 + l16) * 64 + (((4 + quad) ^ sx) * 8)];
#pragma unroll
      for (int mt = 0; mt < 2; ++mt) {
        f32x4 s = {};
        s = MFMA_BF16(kf0, qf[mt][0], s);
        s = MFMA_BF16(kf1, qf[mt][1], s);
        const float p0 = __builtin_amdgcn_exp2f(s[0]);
        const float p1 = __builtin_amdgcn_exp2f(s[1]);
        const float p2 = __builtin_amdgcn_exp2f(s[2]);
        const float p3 = __builtin_amdgcn_exp2f(s[3]);
        uint2 pk;
        pk.x = __builtin_amdgcn_perm(fbits(p1), fbits(p0), 0x07060302);  // [bf16(p1)|bf16(p0)]
        pk.y = __builtin_amdgcn_perm(fbits(p3), fbits(p2), 0x07060302);
        // logical col = nt*16 + quad*4 (+r): chunk = nt*2+(quad>>1), in-chunk off = (quad&1)*4
        *(uint2*)&Ps[(w * 32 + mt * 16 + l16) * 64 +
                     (((nt * 2 + (quad >> 1)) ^ sx) * 8) + (quad & 1) * 4] = pk;
      }
    }

    // ---- O += P·V; row-sums via ones-B MFMA (sums truncated bf16 P -> bias cancels) ----
#pragma unroll
    for (int kc = 0; kc < 2; ++kc) {
      bf16x8 pf[2];
#pragma unroll
      for (int mt = 0; mt < 2; ++mt) {
        pf[mt] = *(const bf16x8*)&Ps[(w * 32 + mt * 16 + l16) * 64 + (((kc * 4 + quad) ^ sx) * 8)];
        lacc[mt] = MFMA_BF16(pf[mt], ones, lacc[mt]);
      }
#pragma unroll
      for (int dt = 0; dt < 4; ++dt) {
        bf16x8 vf = *(const bf16x8*)&VTs[(dt * 16 + l16) * 64 + (((kc * 4 + quad) ^ sx) * 8)];
#pragma unroll
        for (int mt = 0; mt < 2; ++mt)
          oacc[mt][dt] = MFMA_BF16(pf[mt], vf, oacc[mt][dt]);
      }
    }
    __builtin_amdgcn_s_setprio(0);
  }

  // ---- normalize + store; lacc[mt][r] is lsum for q=mt*16+quad*4+r (same rows as oacc) ----
#pragma unroll
  for (int mt = 0; mt < 2; ++mt) {
    float linv[4];
#pragma unroll
    for (int r = 0; r < 4; ++r) linv[r] = 1.0f / lacc[mt][r];
#pragma unroll
    for (int dt = 0; dt < 4; ++dt)
#pragma unroll
      for (int r = 0; r < 4; ++r)
        O[(size_t)(b * S + q0 + mt * 16 + quad * 4 + r) * HID + h * HD + dt * 16 + l16] =
            __float2bfloat16(oacc[mt][dt][r] * linv[r]);
  }
}

extern "C" void kernel_launch(void* const* d_in, const int* in_sizes, int n_in,
                              void* d_out, int out_size, void* d_ws, size_t ws_size,
                              hipStream_t stream) {
  const float* hidden = (const float*)d_in[0];
  const float* Wq = (const float*)d_in[1];
  const float* bq = (const float*)d_in[2];
  const float* Wk = (const float*)d_in[3];
  const float* bk = (const float*)d_in[4];
  const float* Wv = (const float*)d_in[5];
  const float* bv = (const float*)d_in[6];
  const float* Wo = (const float*)d_in[7];
  const float* bo = (const float*)d_in[8];
  float* out = (float*)d_out;

  constexpr int B = 2, S = 2048, HID = 2048, KV = 512, QKVN = 3072;
  constexpr int M = B * S;  // 4096
  const float c1 = 0.125f * 1.44269504089f;

  char* ws = (char*)d_ws;
  bf16_t* hiddenB = (bf16_t*)ws; ws += (size_t)M * HID * 2;
  bf16_t* WqkvT = (bf16_t*)ws;   ws += (size_t)QKVN * HID * 2;
  bf16_t* WoT = (bf16_t*)ws;     ws += (size_t)HID * HID * 2;
  bf16_t* qkv = (bf16_t*)ws;     ws += (size_t)M * QKVN * 2;
  bf16_t* vT = (bf16_t*)ws;      ws += (size_t)M * KV * 2;
  bf16_t* attn = (bf16_t*)ws;    ws += (size_t)M * HID * 2;
  float* bqkv = (float*)ws;      ws += QKVN * 4;

  // one fused prep launch: cast + 4 weight transposes (64x64 tiles) + bias concat
  prep<<<8192 + 2560 + 12, 256, 0, stream>>>(hidden, Wq, Wk, Wv, Wo, bq, bk, bv,
                                             hiddenB, WqkvT, WoT, bqkv, c1);

  // QKV projection; v-columns written directly to vT (transposed) in the epilogue
  gemm_bt<bf16_t><<<dim3(QKVN / 128, M / 128), 256, 0, stream>>>(
      hiddenB, WqkvT, bqkv, qkv, vT, M, QKVN, HID);

  gqa_attn<<<dim3(S / 64, 16, B), 256, 0, stream>>>(qkv, vT, attn);

  gemm_bt<float><<<dim3(HID / 128, M / 128), 256, 0, stream>>>(
      attn, WoT, bo, out, (bf16_t*)nullptr, M, HID, HID);
}

// Round 3
// 301.660 us; speedup vs baseline: 1.0029x; 1.0029x over previous
//
#include <hip/hip_runtime.h>
#include <hip/hip_bf16.h>
#include <math.h>

typedef __bf16 bf16x8 __attribute__((ext_vector_type(8)));
typedef float f32x4 __attribute__((ext_vector_type(4)));
typedef __hip_bfloat16 bf16_t;

#define MFMA_BF16(a, b, c) __builtin_amdgcn_mfma_f32_16x16x32_bf16((a), (b), (c), 0, 0, 0)

// async global->LDS, 16B per lane; LDS dest = wave-uniform base + lane*16
__device__ __forceinline__ void async_copy16(const bf16_t* g, bf16_t* lds_base) {
  __builtin_amdgcn_global_load_lds(
      (const __attribute__((address_space(1))) unsigned int*)g,
      (__attribute__((address_space(3))) unsigned int*)lds_base,
      16, 0, 0);
}

__device__ __forceinline__ unsigned fbits(float x) { return __builtin_bit_cast(unsigned, x); }

// ---------------- fused prep: cast hidden, transpose 4 weights, concat bias ----------------
__global__ __launch_bounds__(256) void prep(
    const float* __restrict__ hidden, const float* __restrict__ Wq, const float* __restrict__ Wk,
    const float* __restrict__ Wv, const float* __restrict__ Wo,
    const float* __restrict__ bq, const float* __restrict__ bk, const float* __restrict__ bv,
    bf16_t* __restrict__ hiddenB, bf16_t* __restrict__ WqkvT, bf16_t* __restrict__ WoT,
    float* __restrict__ bqkv, float c1) {
  __shared__ float tile[64][65];
  int bid = blockIdx.x;
  const int t = threadIdx.x;
  if (bid < 8192) {  // cast hidden f32 -> bf16, float4 per thread
    const int i = bid * 256 + t;
    float4 v = ((const float4*)hidden)[i];
    union { bf16_t h[4]; ushort4 u; } cv;
    cv.h[0] = __float2bfloat16(v.x);
    cv.h[1] = __float2bfloat16(v.y);
    cv.h[2] = __float2bfloat16(v.z);
    cv.h[3] = __float2bfloat16(v.w);
    ((ushort4*)hiddenB)[i] = cv.u;
    return;
  }
  bid -= 8192;
  if (bid >= 2560) {  // bias concat: 12 blocks x 256 = 3072
    const int i = (bid - 2560) * 256 + t;
    float v;
    if (i < 2048) v = bq[i] * c1;
    else if (i < 2560) v = bk[i - 2048];
    else v = bv[i - 2560];
    bqkv[i] = v;
    return;
  }
  // weight transpose: in [2048][C] -> out [C][2048], 64x64 tiles
  const float* src;
  bf16_t* dst;
  int Cc, bx, by;
  float scale = 1.0f;
  if (bid < 1024) { src = Wq; dst = WqkvT; Cc = 2048; bx = bid & 31; by = bid >> 5; scale = c1; }
  else if (bid < 1280) { bid -= 1024; src = Wk; dst = WqkvT + (size_t)2048 * 2048; Cc = 512; bx = bid & 7; by = bid >> 3; }
  else if (bid < 1536) { bid -= 1280; src = Wv; dst = WqkvT + (size_t)2560 * 2048; Cc = 512; bx = bid & 7; by = bid >> 3; }
  else { bid -= 1536; src = Wo; dst = WoT; Cc = 2048; bx = bid & 31; by = bid >> 5; }
  const int tx = t & 63, ty = t >> 6;
  const int c0 = bx * 64, r0 = by * 64;
#pragma unroll
  for (int i = ty; i < 64; i += 4)
    tile[i][tx] = src[(size_t)(r0 + i) * Cc + c0 + tx];
  __syncthreads();
#pragma unroll
  for (int i = ty; i < 64; i += 4)
    dst[(size_t)(c0 + i) * 2048 + r0 + tx] = __float2bfloat16(tile[tx][i] * scale);
}

// ---------------- GEMM v7 (128^2, 2-barrier): kept for gemm2 ----------------
template <typename TOUT>
__global__ __launch_bounds__(256, 3) void gemm_bt(
    const bf16_t* __restrict__ A, const bf16_t* __restrict__ Bt,
    const float* __restrict__ bias, TOUT* __restrict__ C, bf16_t* __restrict__ vTp,
    int M, int N, int K) {
  __shared__ alignas(16) bf16_t As[128 * 64];
  __shared__ alignas(16) bf16_t Bs[128 * 64];

  const int tid = threadIdx.x;
  const int w = tid >> 6, lane = tid & 63;
  const int quad = lane >> 4, l16 = lane & 15;
  const int wm = w >> 1, wn = w & 1;
  const int m0 = blockIdx.y * 128, n0 = blockIdx.x * 128;

  f32x4 acc[4][4] = {};

  const int rr = lane >> 3;                 // row within 8-row staging chunk
  const int scol = ((lane & 7) ^ rr) * 8;   // swizzled SOURCE col (bf16 units)
  const int sx = l16 & 7;                   // row&7 for fragment reads

  for (int k0 = 0; k0 < K; k0 += 64) {
    __syncthreads();
#pragma unroll
    for (int c = 0; c < 4; ++c) {
      const int r = w * 32 + c * 8 + rr;
      async_copy16(A + (size_t)(m0 + r) * K + k0 + scol, &As[(w * 32 + c * 8) * 64]);
      async_copy16(Bt + (size_t)(n0 + r) * K + k0 + scol, &Bs[(w * 32 + c * 8) * 64]);
    }
    __syncthreads();

#pragma unroll
    for (int kh = 0; kh < 2; ++kh) {
      bf16x8 af[4], bf[4];
#pragma unroll
      for (int i = 0; i < 4; ++i) {
        af[i] = *(const bf16x8*)&As[(wm * 64 + i * 16 + l16) * 64 + (((kh * 4 + quad) ^ sx) * 8)];
        bf[i] = *(const bf16x8*)&Bs[(wn * 64 + i * 16 + l16) * 64 + (((kh * 4 + quad) ^ sx) * 8)];
      }
#pragma unroll
      for (int i = 0; i < 4; ++i)
#pragma unroll
        for (int j = 0; j < 4; ++j)
          acc[i][j] = MFMA_BF16(af[i], bf[j], acc[i][j]);
    }
  }

  if (vTp != nullptr && n0 >= 2560) {
#pragma unroll
    for (int i = 0; i < 4; ++i) {
      const int row = m0 + wm * 64 + i * 16 + quad * 4;
      const int bb = row >> 11, s = row & 2047;
#pragma unroll
      for (int j = 0; j < 4; ++j) {
        const int col = n0 + wn * 64 + j * 16 + l16;
        const float bv = bias[col];
        union { bf16_t h[4]; ushort4 u; } cv;
#pragma unroll
        for (int r = 0; r < 4; ++r) cv.h[r] = __float2bfloat16(acc[i][j][r] + bv);
        *(ushort4*)&vTp[((size_t)bb * 512 + (col - 2560)) * 2048 + s] = cv.u;
      }
    }
    return;
  }

#pragma unroll
  for (int i = 0; i < 4; ++i) {
    const int row = m0 + wm * 64 + i * 16 + quad * 4;
#pragma unroll
    for (int j = 0; j < 4; ++j) {
      const int col = n0 + wn * 64 + j * 16 + l16;
      const float bv = bias[col];
#pragma unroll
      for (int r = 0; r < 4; ++r) {
        const float val = acc[i][j][r] + bv;
        if constexpr (__is_same(TOUT, float)) {
          C[(size_t)(row + r) * N + col] = val;
        } else {
          C[(size_t)(row + r) * N + col] = __float2bfloat16(val);
        }
      }
    }
  }
}

// ---------------- GEMM v9: 256^2 8-phase counted-vmcnt (T2+T3+T4+T5) for gemm1 ----------------
// M=4096, N=3072, K=2048 hardcoded. Grid (12,16)=192 blocks, 512 thr (8 waves, 2M x 4N),
// LDS 128KB (2 dbuf x [256][64] bf16 per operand). Per iter: 2 K-tiles, 8 phases.
// Race-free stage schedule (each stage targets a region last READ >=2 barriers earlier):
//   P1:(kt+1).A0  P2:(kt+1).A1  P3:(kt+2).B0  P4:(kt+2).B1   [vmcnt(4)]
//   P5:(kt+2).A0  P6:(kt+2).A1  P7:(kt+3).B0  P8:(kt+3).B1   [vmcnt(4)]
// B read once per K-tile (first phase, held in regs); A quadrant read per phase.
// vmcnt(4) = 2 newest half-tiles (4 loads) stay in flight -> no drain (T4).
// Raw s_barrier (no lgkm/vm drain) + sched_barrier(0) pins (rule #18).
// Tail: stage-tile indices masked &31 (harmless re-stage of tile 0/1); vmcnt(0) before
// epilogue so no in-flight gload_lds lands after LDS dealloc.
__global__ __launch_bounds__(512, 2) void gemm256(
    const bf16_t* __restrict__ A, const bf16_t* __restrict__ Bt,
    const float* __restrict__ bias, bf16_t* __restrict__ C, bf16_t* __restrict__ vTp) {
  constexpr int N = 3072, K = 2048;
  __shared__ alignas(16) bf16_t As[2 * 256 * 64];
  __shared__ alignas(16) bf16_t Bs[2 * 256 * 64];

  const int tid = threadIdx.x;
  const int w = tid >> 6, lane = tid & 63;
  const int quad = lane >> 4, l16 = lane & 15;
  const int wm = w >> 2, wn = w & 3;
  const int m0 = blockIdx.y * 256, n0 = blockIdx.x * 256;

  const int rr = lane >> 3, c7 = lane & 7;
  const int scol = (c7 ^ rr) * 8;  // inverse-swizzled SOURCE col (bf16 units)
  const int sx = l16 & 7;          // row&7 for fragment reads

  // stage one 128-row half-tile (2 x global_load_lds per wave)
  auto stA = [&](int t, int h) {
    const int kb = (t & 31) * 64;
    const int rbase = h * 128 + w * 8;
    bf16_t* d0 = &As[(t & 1) * (256 * 64) + rbase * 64];
    const bf16_t* s0 = A + (size_t)(m0 + rbase + rr) * K + kb + scol;
    async_copy16(s0, d0);
    async_copy16(s0 + (size_t)64 * K, d0 + 64 * 64);
  };
  auto stB = [&](int t, int h) {
    const int kb = (t & 31) * 64;
    const int rbase = h * 128 + w * 8;
    bf16_t* d0 = &Bs[(t & 1) * (256 * 64) + rbase * 64];
    const bf16_t* s0 = Bt + (size_t)(n0 + rbase + rr) * K + kb + scol;
    async_copy16(s0, d0);
    async_copy16(s0 + (size_t)64 * K, d0 + 64 * 64);
  };

  f32x4 acc[4][2][4] = {};  // [phase/quadrant][mi][ni]

  // prologue: tile0 fully staged, tile1.B in flight (newest 4 loads) -> vmcnt(4)
  stB(0, 0); stB(0, 1); stA(0, 0); stA(0, 1);
  stB(1, 0); stB(1, 1);
  asm volatile("s_waitcnt vmcnt(4)" ::: "memory");
  __builtin_amdgcn_sched_barrier(0);
  __builtin_amdgcn_s_barrier();
  __builtin_amdgcn_sched_barrier(0);

  for (int it = 0; it < 16; ++it) {
    const int kt = it * 2;
#pragma unroll
    for (int kg = 0; kg < 2; ++kg) {
      const int ta = (kt + kg + 1) & 31;  // stA target tile
      const int tb = (kt + kg + 2) & 31;  // stB target tile
      const bf16_t* Asb = &As[kg * (256 * 64)];
      const bf16_t* Bsb = &Bs[kg * (256 * 64)];
      bf16x8 b[4][2];
#pragma unroll
      for (int p = 0; p < 4; ++p) {
        // ---- ds reads ----
        if (p == 0) {
#pragma unroll
          for (int ni = 0; ni < 4; ++ni)
#pragma unroll
            for (int kk = 0; kk < 2; ++kk)
              b[ni][kk] = *(const bf16x8*)&Bsb[(wn * 64 + ni * 16 + l16) * 64 +
                                               (((kk * 4 + quad) ^ sx) * 8)];
        }
        bf16x8 a[2][2];
#pragma unroll
        for (int mi = 0; mi < 2; ++mi)
#pragma unroll
          for (int kk = 0; kk < 2; ++kk)
            a[mi][kk] = *(const bf16x8*)&Asb[(wm * 128 + p * 32 + mi * 16 + l16) * 64 +
                                             (((kk * 4 + quad) ^ sx) * 8)];
        // ---- stage slot (1 half-tile) ----
        if (p == 0) stA(ta, 0);
        else if (p == 1) stA(ta, 1);
        else if (p == 2) stB(tb, 0);
        else stB(tb, 1);
        __builtin_amdgcn_sched_barrier(0);
        __builtin_amdgcn_s_barrier();
        __builtin_amdgcn_sched_barrier(0);
        asm volatile("s_waitcnt lgkmcnt(0)" ::: "memory");
        __builtin_amdgcn_sched_barrier(0);
        __builtin_amdgcn_s_setprio(1);
#pragma unroll
        for (int kk = 0; kk < 2; ++kk)
#pragma unroll
          for (int mi = 0; mi < 2; ++mi)
#pragma unroll
            for (int ni = 0; ni < 4; ++ni)
              acc[p][mi][ni] = MFMA_BF16(a[mi][kk], b[ni][kk], acc[p][mi][ni]);
        __builtin_amdgcn_s_setprio(0);
        __builtin_amdgcn_sched_barrier(0);
        if (p == 3) {
          asm volatile("s_waitcnt vmcnt(4)" ::: "memory");
          __builtin_amdgcn_sched_barrier(0);
        }
        __builtin_amdgcn_s_barrier();
        __builtin_amdgcn_sched_barrier(0);
      }
    }
  }

  // drain staging loads before LDS goes away / epilogue
  asm volatile("s_waitcnt vmcnt(0)" ::: "memory");
  __builtin_amdgcn_sched_barrier(0);

  if (n0 >= 2560) {
    // v-columns -> vT[b][col-2560][s]; rows are b*2048+s, 4 consecutive s per lane
#pragma unroll
    for (int p = 0; p < 4; ++p)
#pragma unroll
      for (int mi = 0; mi < 2; ++mi) {
        const int row4 = m0 + wm * 128 + p * 32 + mi * 16 + quad * 4;
        const int bb = row4 >> 11, s = row4 & 2047;
#pragma unroll
        for (int ni = 0; ni < 4; ++ni) {
          const int col = n0 + wn * 64 + ni * 16 + l16;
          const float bv = bias[col];
          union { bf16_t h[4]; ushort4 u; } cv;
#pragma unroll
          for (int r = 0; r < 4; ++r) cv.h[r] = __float2bfloat16(acc[p][mi][ni][r] + bv);
          *(ushort4*)&vTp[((size_t)bb * 512 + (col - 2560)) * 2048 + s] = cv.u;
        }
      }
    return;
  }

#pragma unroll
  for (int p = 0; p < 4; ++p)
#pragma unroll
    for (int mi = 0; mi < 2; ++mi) {
      const int row4 = m0 + wm * 128 + p * 32 + mi * 16 + quad * 4;
#pragma unroll
      for (int ni = 0; ni < 4; ++ni) {
        const int col = n0 + wn * 64 + ni * 16 + l16;
        const float bv = bias[col];
#pragma unroll
        for (int r = 0; r < 4; ++r)
          C[(size_t)(row4 + r) * N + col] = __float2bfloat16(acc[p][mi][ni][r] + bv);
      }
    }
}

// ---------------- GQA flash attention (v8: T14 reg-staged prefetch + T5 setprio) ----------------
// QKV: [B*S][3072] bf16 (q at col h*64, Wq pre-scaled by 0.125*log2e; k at 2048+g*64)
// VT: [B*512][2048] bf16 (row b*512+g*64+d, col s); O: [B*S][2048] bf16
// grid (S/64, NH/2, B) = 1024 blocks = 4/CU; 256 threads. Block covers 64 q-rows x 2 heads.
// T14: global_load_dwordx4 for tile t+1 issued right after tile t's ds_writes -> ~400cy
// L2 latency hides under the compute phase. Measured R2: 88.2 -> 81.0 us, MfmaUtil 40.6.
__global__ __launch_bounds__(256, 4) void gqa_attn(
    const bf16_t* __restrict__ QKV, const bf16_t* __restrict__ VT, bf16_t* __restrict__ O) {
  constexpr int S = 2048, HID = 2048, QKVS = 3072, HD = 64;
  const int tid = threadIdx.x;
  const int w = tid >> 6, lane = tid & 63;
  const int quad = lane >> 4, l16 = lane & 15;
  const int hp = blockIdx.y, b = blockIdx.z;
  const int h = hp * 2 + (w & 1);       // wave's head
  const int g = hp >> 1;                // shared KV group (rep=4: heads 4g..4g+3)
  const int q0 = blockIdx.x * 64 + (w >> 1) * 32;  // wave's 32 q rows

  __shared__ alignas(16) bf16_t Ks[64 * 64];
  __shared__ alignas(16) bf16_t VTs[64 * 64];
  __shared__ alignas(16) bf16_t Ps[128 * 64];

  // Q fragments in registers (B-operand layout: n=l16 -> q, k=quad*8+j); pre-scaled
  bf16x8 qf[2][2];
#pragma unroll
  for (int mt = 0; mt < 2; ++mt)
#pragma unroll
    for (int ks = 0; ks < 2; ++ks)
      qf[mt][ks] = *(const bf16x8*)&QKV[(size_t)(b * S + q0 + mt * 16 + l16) * QKVS +
                                        h * HD + ks * 32 + quad * 8];

  const int rr = lane >> 3, c7 = lane & 7;
  const int sx = l16 & 7;

  const bf16_t* Kbase = QKV + (size_t)b * S * QKVS + 2048 + g * HD;
  const bf16_t* Vbase = VT + (size_t)(b * 512 + g * HD) * S;

  // reg-staging geometry: this thread owns rows srow and srow+8 of the 64-row tile,
  // 16B chunk c7; LDS dest chunk XOR-swizzled with row&7 (= rr).
  const int srow = w * 16 + rr;
  const bf16_t* kp0 = Kbase + (size_t)srow * QKVS + c7 * 8;
  const bf16_t* kp1 = kp0 + (size_t)8 * QKVS;
  const bf16_t* vp0 = Vbase + (size_t)srow * S + c7 * 8;
  const bf16_t* vp1 = vp0 + (size_t)8 * S;
  bf16_t* KsW0 = &Ks[(srow)*64 + (c7 ^ rr) * 8];
  bf16_t* KsW1 = KsW0 + 8 * 64;
  bf16_t* VsW0 = &VTs[(srow)*64 + (c7 ^ rr) * 8];
  bf16_t* VsW1 = VsW0 + 8 * 64;

  f32x4 oacc[2][4] = {};
  f32x4 lacc[2] = {};
  bf16x8 ones;
#pragma unroll
  for (int j = 0; j < 8; ++j) ones[j] = (__bf16)1.0f;

  // prologue: issue tile-0 loads
  uint4 kr0 = *(const uint4*)kp0;
  uint4 kr1 = *(const uint4*)kp1;
  uint4 vr0 = *(const uint4*)vp0;
  uint4 vr1 = *(const uint4*)vp1;

  for (int s0 = 0; s0 < S; s0 += 64) {
    __syncthreads();  // all waves done reading the previous tile's LDS
    *(uint4*)KsW0 = kr0;
    *(uint4*)KsW1 = kr1;
    *(uint4*)VsW0 = vr0;
    *(uint4*)VsW1 = vr1;
    // issue next-tile loads now; they stay in flight across the whole compute phase.
    const int sn = (s0 + 64) & (S - 1);
    kr0 = *(const uint4*)(kp0 + (size_t)sn * QKVS);
    kr1 = *(const uint4*)(kp1 + (size_t)sn * QKVS);
    vr0 = *(const uint4*)(vp0 + sn);
    vr1 = *(const uint4*)(vp1 + sn);
    __syncthreads();  // ds_writes visible to all waves

    __builtin_amdgcn_s_setprio(1);
    // ---- S^T = K·Q^T (row=kv=quad*4+r, col=q=l16); p=exp2(s); pack(trunc) -> Ps[q][kv] ----
#pragma unroll
    for (int nt = 0; nt < 4; ++nt) {
      bf16x8 kf0 = *(const bf16x8*)&Ks[(nt * 16 + l16) * 64 + ((quad ^ sx) * 8)];
      bf16x8 kf1 = *(const bf16x8*)&Ks[(nt * 16 + l16) * 64 + (((4 + quad) ^ sx) * 8)];
#pragma unroll
      for (int mt = 0; mt < 2; ++mt) {
        f32x4 s = {};
        s = MFMA_BF16(kf0, qf[mt][0], s);
        s = MFMA_BF16(kf1, qf[mt][1], s);
        const float p0 = __builtin_amdgcn_exp2f(s[0]);
        const float p1 = __builtin_amdgcn_exp2f(s[1]);
        const float p2 = __builtin_amdgcn_exp2f(s[2]);
        const float p3 = __builtin_amdgcn_exp2f(s[3]);
        uint2 pk;
        pk.x = __builtin_amdgcn_perm(fbits(p1), fbits(p0), 0x07060302);  // [bf16(p1)|bf16(p0)]
        pk.y = __builtin_amdgcn_perm(fbits(p3), fbits(p2), 0x07060302);
        *(uint2*)&Ps[(w * 32 + mt * 16 + l16) * 64 +
                     (((nt * 2 + (quad >> 1)) ^ sx) * 8) + (quad & 1) * 4] = pk;
      }
    }

    // ---- O += P·V; row-sums via ones-B MFMA (sums truncated bf16 P -> bias cancels) ----
#pragma unroll
    for (int kc = 0; kc < 2; ++kc) {
      bf16x8 pf[2];
#pragma unroll
      for (int mt = 0; mt < 2; ++mt) {
        pf[mt] = *(const bf16x8*)&Ps[(w * 32 + mt * 16 + l16) * 64 + (((kc * 4 + quad) ^ sx) * 8)];
        lacc[mt] = MFMA_BF16(pf[mt], ones, lacc[mt]);
      }
#pragma unroll
      for (int dt = 0; dt < 4; ++dt) {
        bf16x8 vf = *(const bf16x8*)&VTs[(dt * 16 + l16) * 64 + (((kc * 4 + quad) ^ sx) * 8)];
#pragma unroll
        for (int mt = 0; mt < 2; ++mt)
          oacc[mt][dt] = MFMA_BF16(pf[mt], vf, oacc[mt][dt]);
      }
    }
    __builtin_amdgcn_s_setprio(0);
  }

  // ---- normalize + store ----
#pragma unroll
  for (int mt = 0; mt < 2; ++mt) {
    float linv[4];
#pragma unroll
    for (int r = 0; r < 4; ++r) linv[r] = 1.0f / lacc[mt][r];
#pragma unroll
    for (int dt = 0; dt < 4; ++dt)
#pragma unroll
      for (int r = 0; r < 4; ++r)
        O[(size_t)(b * S + q0 + mt * 16 + quad * 4 + r) * HID + h * HD + dt * 16 + l16] =
            __float2bfloat16(oacc[mt][dt][r] * linv[r]);
  }
}

extern "C" void kernel_launch(void* const* d_in, const int* in_sizes, int n_in,
                              void* d_out, int out_size, void* d_ws, size_t ws_size,
                              hipStream_t stream) {
  const float* hidden = (const float*)d_in[0];
  const float* Wq = (const float*)d_in[1];
  const float* bq = (const float*)d_in[2];
  const float* Wk = (const float*)d_in[3];
  const float* bk = (const float*)d_in[4];
  const float* Wv = (const float*)d_in[5];
  const float* bv = (const float*)d_in[6];
  const float* Wo = (const float*)d_in[7];
  const float* bo = (const float*)d_in[8];
  float* out = (float*)d_out;

  constexpr int B = 2, S = 2048, HID = 2048, KV = 512, QKVN = 3072;
  constexpr int M = B * S;  // 4096
  const float c1 = 0.125f * 1.44269504089f;

  char* ws = (char*)d_ws;
  bf16_t* hiddenB = (bf16_t*)ws; ws += (size_t)M * HID * 2;
  bf16_t* WqkvT = (bf16_t*)ws;   ws += (size_t)QKVN * HID * 2;
  bf16_t* WoT = (bf16_t*)ws;     ws += (size_t)HID * HID * 2;
  bf16_t* qkv = (bf16_t*)ws;     ws += (size_t)M * QKVN * 2;
  bf16_t* vT = (bf16_t*)ws;      ws += (size_t)M * KV * 2;
  bf16_t* attn = (bf16_t*)ws;    ws += (size_t)M * HID * 2;
  float* bqkv = (float*)ws;      ws += QKVN * 4;

  // one fused prep launch: cast + 4 weight transposes (64x64 tiles) + bias concat
  prep<<<8192 + 2560 + 12, 256, 0, stream>>>(hidden, Wq, Wk, Wv, Wo, bq, bk, bv,
                                             hiddenB, WqkvT, WoT, bqkv, c1);

  // QKV projection: 256^2 8-phase kernel; v-columns written transposed to vT
  gemm256<<<dim3(QKVN / 256, M / 256), 512, 0, stream>>>(hiddenB, WqkvT, bqkv, qkv, vT);

  gqa_attn<<<dim3(S / 64, 16, B), 256, 0, stream>>>(qkv, vT, attn);

  gemm_bt<float><<<dim3(HID / 128, M / 128), 256, 0, stream>>>(
      attn, WoT, bo, out, (bf16_t*)nullptr, M, HID, HID);
}